// Round 1
// baseline (601.443 us; speedup 1.0000x reference)
//
#include <hip/hip_runtime.h>

#define BB 4
#define CIN 64
#define COUT 64
#define NN 40960
#define KK 16
#define SBLK 512

__global__ __launch_bounds__(256) void k_count(const int* __restrict__ idx, int* __restrict__ cnt) {
    int t = blockIdx.x * 256 + threadIdx.x;
    if (t < BB * NN * KK) {
        int b = t / (NN * KK);
        int m = idx[t];
        atomicAdd(&cnt[b * NN + m], 1);
    }
}

// g[b][n][o] = sum_c W[o][c] * feat[b][c][n]
// wave: lane = o; each wave handles 16 consecutive n
__global__ __launch_bounds__(256) void k_gemm(const float* __restrict__ feat,
                                              const float* __restrict__ W,
                                              float* __restrict__ g) {
    const int lane = threadIdx.x & 63;
    const int wave = threadIdx.x >> 6;
    const int gid  = blockIdx.x;              // 0 .. B*N/64 - 1
    const int b    = gid / (NN / 64);
    const int n0   = (gid % (NN / 64)) * 64 + wave * 16;

    float Wrow[64];
#pragma unroll
    for (int c = 0; c < 64; ++c) Wrow[c] = W[lane * 64 + c];

    const float* pcb = feat + (size_t)b * CIN * NN;
    for (int i = 0; i < 16; ++i) {
        int n = n0 + i;
        float acc = 0.f;
#pragma unroll
        for (int c = 0; c < 64; ++c) acc = fmaf(Wrow[c], pcb[c * NN + n], acc);
        g[((size_t)(b * NN + n)) * 64 + lane] = acc;
    }
}

// weighted sums: S1[o] = sum w*v, S2[o] = sum w*v^2, weight = cnt+1 (self ref)
__global__ __launch_bounds__(256) void k_stats(const float* __restrict__ g,
                                               const int* __restrict__ cnt,
                                               double* __restrict__ partials) {
    const int lane = threadIdx.x & 63;
    const int wave = threadIdx.x >> 6;
    const int wid  = blockIdx.x * 4 + wave;   // 0 .. SBLK*4-1
    double s1 = 0.0, s2 = 0.0;
    for (int p = wid; p < BB * NN; p += SBLK * 4) {
        float w  = (float)(cnt[p] + 1);
        float v  = g[(size_t)p * 64 + lane];
        double wv = (double)w * (double)v;
        s1 += wv;
        s2 += wv * (double)v;
    }
    __shared__ double l1[4][64];
    __shared__ double l2[4][64];
    l1[wave][lane] = s1;
    l2[wave][lane] = s2;
    __syncthreads();
    if (wave == 0) {
        double a = l1[0][lane] + l1[1][lane] + l1[2][lane] + l1[3][lane];
        double q = l2[0][lane] + l2[1][lane] + l2[2][lane] + l2[3][lane];
        partials[blockIdx.x * 128 + lane]      = a;
        partials[blockIdx.x * 128 + 64 + lane] = q;
    }
}

__global__ __launch_bounds__(128) void k_finalize(const double* __restrict__ partials,
                                                  const float* __restrict__ gamma,
                                                  const float* __restrict__ beta,
                                                  float* __restrict__ params) {
    const int i = threadIdx.x;  // 0..127
    double s = 0.0;
    for (int blk = 0; blk < SBLK; ++blk) s += partials[blk * 128 + i];
    __shared__ double red[128];
    red[i] = s;
    __syncthreads();
    if (i < 64) {
        const double TOT = (double)BB * NN * (KK + 1);
        double mean = red[i] / TOT;
        double var  = red[64 + i] / TOT - mean * mean;
        double inv  = 1.0 / sqrt(var + 1e-6);
        float scale = (float)inv * gamma[i];
        float shift = beta[i] - (float)mean * scale;
        params[i]      = scale;
        params[64 + i] = shift;
    }
}

// out[b][o][n] = sum over {n, idx[b,n,0..15]} of leakyrelu(g*scale+shift)
__global__ __launch_bounds__(256) void k_final(const float* __restrict__ g,
                                               const int* __restrict__ idx,
                                               const float* __restrict__ params,
                                               float* __restrict__ out) {
    const int lane = threadIdx.x & 63;
    const int wave = threadIdx.x >> 6;
    const int b    = blockIdx.x / (NN / 64);
    const int n0   = (blockIdx.x % (NN / 64)) * 64;
    const float scale = params[lane];
    const float shift = params[64 + lane];

    __shared__ float tile[64][65];
    const float* gb  = g + (size_t)b * NN * 64;
    const int* idxb  = idx + b * NN * KK;

    for (int i = 0; i < 16; ++i) {
        int n = n0 + wave * 16 + i;
        int m_lane = 0;
        if (lane < KK) m_lane = idxb[n * KK + lane];
        float v = gb[(size_t)n * 64 + lane];
        float t = fmaf(v, scale, shift);
        float acc = t >= 0.f ? t : 0.2f * t;
#pragma unroll
        for (int k = 0; k < KK; ++k) {
            int m = __shfl(m_lane, k, 64);
            float vv = gb[(size_t)m * 64 + lane];
            float tt = fmaf(vv, scale, shift);
            acc += tt >= 0.f ? tt : 0.2f * tt;
        }
        tile[wave * 16 + i][lane] = acc;
    }
    __syncthreads();
    const int j   = threadIdx.x & 63;
    const int sub = threadIdx.x >> 6;  // 0..3
#pragma unroll
    for (int ob = 0; ob < 16; ++ob) {
        int o = ob * 4 + sub;
        out[(size_t)(b * 64 + o) * NN + n0 + j] = tile[j][o];
    }
}

extern "C" void kernel_launch(void* const* d_in, const int* in_sizes, int n_in,
                              void* d_out, int out_size, void* d_ws, size_t ws_size,
                              hipStream_t stream) {
    const float* feat  = (const float*)d_in[0];
    const float* W     = (const float*)d_in[1];
    const float* gamma = (const float*)d_in[2];
    const float* beta  = (const float*)d_in[3];
    const int*   idx   = (const int*)d_in[4];
    float* out = (float*)d_out;

    char* ws = (char*)d_ws;
    float* g = (float*)ws;
    size_t off = (size_t)BB * NN * 64 * sizeof(float);       // 41,943,040
    int* cnt = (int*)(ws + off);
    off += (size_t)BB * NN * sizeof(int);                    // +655,360
    double* partials = (double*)(ws + off);
    off += (size_t)SBLK * 128 * sizeof(double);              // +524,288
    float* params = (float*)(ws + off);

    hipMemsetAsync(cnt, 0, (size_t)BB * NN * sizeof(int), stream);
    k_count<<<(BB * NN * KK + 255) / 256, 256, 0, stream>>>(idx, cnt);
    k_gemm<<<(BB * NN) / 64, 256, 0, stream>>>(feat, W, g);
    k_stats<<<SBLK, 256, 0, stream>>>(g, cnt, partials);
    k_finalize<<<1, 128, 0, stream>>>(partials, gamma, beta, params);
    k_final<<<(BB * NN) / 64, 256, 0, stream>>>(g, idx, params, out);
}

// Round 2
// 354.088 us; speedup vs baseline: 1.6986x; 1.6986x over previous
//
#include <hip/hip_runtime.h>

#define BB 4
#define CIN 64
#define COUT 64
#define NN 40960
#define KK 16
#define SBLK 512

__global__ __launch_bounds__(256) void k_count(const int* __restrict__ idx, int* __restrict__ cnt) {
    int t = blockIdx.x * 256 + threadIdx.x;
    if (t < BB * NN * KK) {
        int b = t / (NN * KK);
        int m = idx[t];
        atomicAdd(&cnt[b * NN + m], 1);
    }
}

// g[b][n][o] = sum_c W[o][c] * feat[b][c][n]
// LDS-tiled vector GEMM: block = 64 o x 256 n, thread tile 8x8.
// to = tid&7 -> o = to*8..to*8+7 ; tn = tid>>3 -> n = n0 + tn*8..+7
#define FPAD 264   // 256 + 8 floats row pitch (breaks bank aliasing)
__global__ __launch_bounds__(256) void k_gemm(const float* __restrict__ feat,
                                              const float* __restrict__ W,
                                              float* __restrict__ g) {
    __shared__ float Wt_s[64 * 64];      // Wt_s[c][o] = W[o][c], 16 KB
    __shared__ float feat_s[16 * FPAD];  // 16 c-rows x 256 n (padded), 16.9 KB

    const int tid = threadIdx.x;
    const int b   = blockIdx.x / (NN / 256);
    const int n0  = (blockIdx.x % (NN / 256)) * 256;

    // stage W transposed: e = it*256+tid; o = tid&63 (lane-fast -> conflict-free LDS write)
#pragma unroll
    for (int it = 0; it < 16; ++it) {
        int o = tid & 63;
        int c = it * 4 + (tid >> 6);
        Wt_s[c * 64 + o] = W[o * 64 + c];
    }

    const int to = tid & 7;    // o-thread
    const int tn = tid >> 3;   // n-thread (0..31)

    float acc[8][8];
#pragma unroll
    for (int i = 0; i < 8; ++i)
#pragma unroll
        for (int j = 0; j < 8; ++j) acc[i][j] = 0.f;

    const float* fb = feat + (size_t)b * CIN * NN + n0;

    for (int cc0 = 0; cc0 < 64; cc0 += 16) {
        __syncthreads();
        // stage 16 c-rows x 256 n, coalesced float4 reads
        {
            int row = tid >> 4;          // 0..15
            int col = (tid & 15) * 4;    // 0..60
            const float* src = fb + (size_t)(cc0 + row) * NN + col;
#pragma unroll
            for (int q = 0; q < 4; ++q) {
                float4 v = *(const float4*)(src + q * 64);
                *(float4*)&feat_s[row * FPAD + col + q * 64] = v;
            }
        }
        __syncthreads();

#pragma unroll
        for (int cc = 0; cc < 16; ++cc) {
            int c = cc0 + cc;
            float4 w0 = *(const float4*)&Wt_s[c * 64 + to * 8];
            float4 w1 = *(const float4*)&Wt_s[c * 64 + to * 8 + 4];
            float4 f0 = *(const float4*)&feat_s[cc * FPAD + tn * 8];
            float4 f1 = *(const float4*)&feat_s[cc * FPAD + tn * 8 + 4];
            float wv[8] = {w0.x, w0.y, w0.z, w0.w, w1.x, w1.y, w1.z, w1.w};
            float fv[8] = {f0.x, f0.y, f0.z, f0.w, f1.x, f1.y, f1.z, f1.w};
#pragma unroll
            for (int i = 0; i < 8; ++i)
#pragma unroll
                for (int j = 0; j < 8; ++j)
                    acc[i][j] = fmaf(wv[i], fv[j], acc[i][j]);
        }
    }

    // store: g[(b*NN + n)*64 + o], 8 lanes (to=0..7) cover one 256B row
    float* gb = g + ((size_t)b * NN + n0) * 64;
#pragma unroll
    for (int j = 0; j < 8; ++j) {
        int n = tn * 8 + j;
        float4 s0 = make_float4(acc[0][j], acc[1][j], acc[2][j], acc[3][j]);
        float4 s1 = make_float4(acc[4][j], acc[5][j], acc[6][j], acc[7][j]);
        *(float4*)&gb[(size_t)n * 64 + to * 8]     = s0;
        *(float4*)&gb[(size_t)n * 64 + to * 8 + 4] = s1;
    }
}

// weighted sums: S1[o] = sum w*v, S2[o] = sum w*v^2, weight = cnt+1 (self ref)
__global__ __launch_bounds__(256) void k_stats(const float* __restrict__ g,
                                               const int* __restrict__ cnt,
                                               double* __restrict__ partials) {
    const int lane = threadIdx.x & 63;
    const int wave = threadIdx.x >> 6;
    const int wid  = blockIdx.x * 4 + wave;
    double s1 = 0.0, s2 = 0.0;
    for (int p = wid; p < BB * NN; p += SBLK * 4) {
        float w  = (float)(cnt[p] + 1);
        float v  = g[(size_t)p * 64 + lane];
        double wv = (double)w * (double)v;
        s1 += wv;
        s2 += wv * (double)v;
    }
    __shared__ double l1[4][64];
    __shared__ double l2[4][64];
    l1[wave][lane] = s1;
    l2[wave][lane] = s2;
    __syncthreads();
    if (wave == 0) {
        double a = l1[0][lane] + l1[1][lane] + l1[2][lane] + l1[3][lane];
        double q = l2[0][lane] + l2[1][lane] + l2[2][lane] + l2[3][lane];
        partials[blockIdx.x * 128 + lane]      = a;
        partials[blockIdx.x * 128 + 64 + lane] = q;
    }
}

__global__ __launch_bounds__(1024) void k_finalize(const double* __restrict__ partials,
                                                   const float* __restrict__ gamma,
                                                   const float* __restrict__ beta,
                                                   float* __restrict__ params) {
    const int i = threadIdx.x & 127;   // stat slot
    const int r = threadIdx.x >> 7;    // 0..7
    double s = 0.0;
    for (int blk = r; blk < SBLK; blk += 8) s += partials[blk * 128 + i];
    __shared__ double red[8][128];
    red[r][i] = s;
    __syncthreads();
    if (threadIdx.x < 64) {
        const int o = threadIdx.x;
        double s1 = 0.0, s2 = 0.0;
#pragma unroll
        for (int rr = 0; rr < 8; ++rr) { s1 += red[rr][o]; s2 += red[rr][64 + o]; }
        const double TOT = (double)BB * NN * (KK + 1);
        double mean = s1 / TOT;
        double var  = s2 / TOT - mean * mean;
        double inv  = 1.0 / sqrt(var + 1e-6);
        float scale = (float)inv * gamma[o];
        float shift = beta[o] - (float)mean * scale;
        params[o]      = scale;
        params[64 + o] = shift;
    }
}

// out[b][o][n] = sum over {n, idx[b,n,0..15]} of leakyrelu(g*scale+shift)
__global__ __launch_bounds__(256) void k_final(const float* __restrict__ g,
                                               const int* __restrict__ idx,
                                               const float* __restrict__ params,
                                               float* __restrict__ out) {
    const int lane = threadIdx.x & 63;
    const int wave = threadIdx.x >> 6;
    const int b    = blockIdx.x / (NN / 64);
    const int n0   = (blockIdx.x % (NN / 64)) * 64;
    const float scale = params[lane];
    const float shift = params[64 + lane];

    __shared__ float tile[64][65];
    const float* gb  = g + (size_t)b * NN * 64;
    const int* idxb  = idx + b * NN * KK;

    for (int i = 0; i < 16; ++i) {
        int n = n0 + wave * 16 + i;
        int m_lane = 0;
        if (lane < KK) m_lane = idxb[n * KK + lane];
        float v = gb[(size_t)n * 64 + lane];
        float t = fmaf(v, scale, shift);
        float acc = t >= 0.f ? t : 0.2f * t;
#pragma unroll
        for (int k = 0; k < KK; ++k) {
            int m = __shfl(m_lane, k, 64);
            float vv = gb[(size_t)m * 64 + lane];
            float tt = fmaf(vv, scale, shift);
            acc += tt >= 0.f ? tt : 0.2f * tt;
        }
        tile[wave * 16 + i][lane] = acc;
    }
    __syncthreads();
    const int j   = threadIdx.x & 63;
    const int sub = threadIdx.x >> 6;
#pragma unroll
    for (int ob = 0; ob < 16; ++ob) {
        int o = ob * 4 + sub;
        out[(size_t)(b * 64 + o) * NN + n0 + j] = tile[j][o];
    }
}

extern "C" void kernel_launch(void* const* d_in, const int* in_sizes, int n_in,
                              void* d_out, int out_size, void* d_ws, size_t ws_size,
                              hipStream_t stream) {
    const float* feat  = (const float*)d_in[0];
    const float* W     = (const float*)d_in[1];
    const float* gamma = (const float*)d_in[2];
    const float* beta  = (const float*)d_in[3];
    const int*   idx   = (const int*)d_in[4];
    float* out = (float*)d_out;

    char* ws = (char*)d_ws;
    float* g = (float*)ws;
    size_t off = (size_t)BB * NN * 64 * sizeof(float);
    int* cnt = (int*)(ws + off);
    off += (size_t)BB * NN * sizeof(int);
    double* partials = (double*)(ws + off);
    off += (size_t)SBLK * 128 * sizeof(double);
    float* params = (float*)(ws + off);

    hipMemsetAsync(cnt, 0, (size_t)BB * NN * sizeof(int), stream);
    k_count<<<(BB * NN * KK + 255) / 256, 256, 0, stream>>>(idx, cnt);
    k_gemm<<<(BB * NN) / 256, 256, 0, stream>>>(feat, W, g);
    k_stats<<<SBLK, 256, 0, stream>>>(g, cnt, partials);
    k_finalize<<<1, 1024, 0, stream>>>(partials, gamma, beta, params);
    k_final<<<(BB * NN) / 64, 256, 0, stream>>>(g, idx, params, out);
}

// Round 3
// 262.423 us; speedup vs baseline: 2.2919x; 1.3493x over previous
//
#include <hip/hip_runtime.h>

#define BB 4
#define CIN 64
#define COUT 64
#define NN 40960
#define KK 16
#define GBLK (BB * NN / 256)   // 640 k_gemm blocks
#define FPAD 264
#define WPAD 68

__global__ __launch_bounds__(256) void k_count(const int* __restrict__ idx, int* __restrict__ cnt) {
    int t = blockIdx.x * 256 + threadIdx.x;
    if (t < BB * NN * KK) {
        int b = t / (NN * KK);
        int m = idx[t];
        atomicAdd(&cnt[b * NN + m], 1);
    }
}

__device__ __forceinline__ unsigned bf16_rne(float x) {
    unsigned u = __float_as_uint(x);
    return (u + 0x7fffu + ((u >> 16) & 1u)) >> 16;
}

// g[b][n][o] (bf16) = sum_c W[o][c]*feat[b][c][n]; fused weighted stats -> partials[block][128]
__global__ __launch_bounds__(256) void k_gemm(const float* __restrict__ feat,
                                              const float* __restrict__ W,
                                              const int* __restrict__ cnt,
                                              unsigned short* __restrict__ gbf,
                                              float* __restrict__ partials) {
    __shared__ float Wt_s[64 * WPAD];    // Wt_s[c][o], pitch 68
    __shared__ float feat_s[16 * FPAD];  // reused as red[2][64][33] in epilogue

    const int tid = threadIdx.x;
    const int b   = blockIdx.x / (NN / 256);
    const int n0  = (blockIdx.x % (NN / 256)) * 256;

    // stage W: coalesced global read (c lane-fast), transposed LDS write (8-way, once)
#pragma unroll
    for (int it = 0; it < 16; ++it) {
        int c = tid & 63;
        int o = it * 4 + (tid >> 6);
        Wt_s[c * WPAD + o] = W[o * 64 + c];
    }

    const int to = tid & 7;
    const int tn = tid >> 3;

    float acc[8][8];
#pragma unroll
    for (int i = 0; i < 8; ++i)
#pragma unroll
        for (int j = 0; j < 8; ++j) acc[i][j] = 0.f;

    const float* fb = feat + (size_t)b * CIN * NN + n0;

    for (int cc0 = 0; cc0 < 64; cc0 += 16) {
        __syncthreads();
        {
            int row = tid >> 4;
            int col = (tid & 15) * 4;
            const float* src = fb + (size_t)(cc0 + row) * NN + col;
#pragma unroll
            for (int q = 0; q < 4; ++q) {
                float4 v = *(const float4*)(src + q * 64);
                *(float4*)&feat_s[row * FPAD + col + q * 64] = v;
            }
        }
        __syncthreads();

#pragma unroll
        for (int cc = 0; cc < 16; ++cc) {
            int c = cc0 + cc;
            float4 w0 = *(const float4*)&Wt_s[c * WPAD + to * 8];
            float4 w1 = *(const float4*)&Wt_s[c * WPAD + to * 8 + 4];
            float4 f0 = *(const float4*)&feat_s[cc * FPAD + tn * 8];
            float4 f1 = *(const float4*)&feat_s[cc * FPAD + tn * 8 + 4];
            float wv[8] = {w0.x, w0.y, w0.z, w0.w, w1.x, w1.y, w1.z, w1.w};
            float fv[8] = {f0.x, f0.y, f0.z, f0.w, f1.x, f1.y, f1.z, f1.w};
#pragma unroll
            for (int i = 0; i < 8; ++i)
#pragma unroll
                for (int j = 0; j < 8; ++j)
                    acc[i][j] = fmaf(wv[i], fv[j], acc[i][j]);
        }
    }

    // store g as bf16: 8 lanes (to) cover one 128B row
    unsigned short* gb = gbf + ((size_t)b * NN + n0) * 64;
#pragma unroll
    for (int j = 0; j < 8; ++j) {
        int n = tn * 8 + j;
        uint4 pk;
        pk.x = bf16_rne(acc[0][j]) | (bf16_rne(acc[1][j]) << 16);
        pk.y = bf16_rne(acc[2][j]) | (bf16_rne(acc[3][j]) << 16);
        pk.z = bf16_rne(acc[4][j]) | (bf16_rne(acc[5][j]) << 16);
        pk.w = bf16_rne(acc[6][j]) | (bf16_rne(acc[7][j]) << 16);
        *(uint4*)&gb[(size_t)n * 64 + to * 8] = pk;
    }

    // fused weighted stats: w = cnt+1
    float wgt[8];
    {
        const int4* cp = (const int4*)&cnt[b * NN + n0 + tn * 8];
        int4 c0 = cp[0], c1 = cp[1];
        wgt[0] = (float)(c0.x + 1); wgt[1] = (float)(c0.y + 1);
        wgt[2] = (float)(c0.z + 1); wgt[3] = (float)(c0.w + 1);
        wgt[4] = (float)(c1.x + 1); wgt[5] = (float)(c1.y + 1);
        wgt[6] = (float)(c1.z + 1); wgt[7] = (float)(c1.w + 1);
    }
    float s1[8], s2[8];
#pragma unroll
    for (int i = 0; i < 8; ++i) { s1[i] = 0.f; s2[i] = 0.f; }
#pragma unroll
    for (int j = 0; j < 8; ++j)
#pragma unroll
        for (int i = 0; i < 8; ++i) {
            float wv = wgt[j] * acc[i][j];
            s1[i] += wv;
            s2[i] += wv * acc[i][j];
        }

    __syncthreads();
    float* red = feat_s;  // [2][64][33]
#pragma unroll
    for (int i = 0; i < 8; ++i) {
        int o = to * 8 + i;
        red[o * 33 + tn]        = s1[i];
        red[2112 + o * 33 + tn] = s2[i];
    }
    __syncthreads();
    if (tid < 128) {
        int arr = tid >> 6, o = tid & 63;
        const float* base = red + arr * 2112 + o * 33;
        float s = 0.f;
#pragma unroll
        for (int t = 0; t < 32; ++t) s += base[t];
        partials[blockIdx.x * 128 + arr * 64 + o] = s;
    }
}

__global__ __launch_bounds__(1024) void k_finalize(const float* __restrict__ partials,
                                                   const float* __restrict__ gamma,
                                                   const float* __restrict__ beta,
                                                   float* __restrict__ params) {
    const int i = threadIdx.x & 127;
    const int r = threadIdx.x >> 7;  // 0..7
    double a0 = 0, a1 = 0, a2 = 0, a3 = 0;
    for (int base = r; base < GBLK; base += 32) {
        a0 += (double)partials[(base)      * 128 + i];
        a1 += (double)partials[(base + 8)  * 128 + i];
        a2 += (double)partials[(base + 16) * 128 + i];
        a3 += (double)partials[(base + 24) * 128 + i];
    }
    __shared__ double red[8][128];
    red[r][i] = (a0 + a1) + (a2 + a3);
    __syncthreads();
    if (threadIdx.x < 64) {
        const int o = threadIdx.x;
        double s1 = 0.0, s2 = 0.0;
#pragma unroll
        for (int rr = 0; rr < 8; ++rr) { s1 += red[rr][o]; s2 += red[rr][64 + o]; }
        const double TOT = (double)BB * NN * (KK + 1);
        double mean = s1 / TOT;
        double var  = s2 / TOT - mean * mean;
        double inv  = 1.0 / sqrt(var + 1e-6);
        float scale = (float)inv * gamma[o];
        float shift = beta[o] - (float)mean * scale;
        params[o]      = scale;
        params[64 + o] = shift;
    }
}

// out[b][o][n] = sum over {n, idx[b,n,:]} of leakyrelu(g*scale+shift)
// wave handles 4 n per iteration: lane = (r=lane>>4 selects n, q=lane&15 selects channel-quad)
__global__ __launch_bounds__(256) void k_final(const unsigned short* __restrict__ gbf,
                                               const int* __restrict__ idx,
                                               const float* __restrict__ params,
                                               float* __restrict__ out) {
    const int tid  = threadIdx.x;
    const int lane = tid & 63;
    const int wave = tid >> 6;
    const int b    = blockIdx.x / (NN / 64);
    const int n0   = (blockIdx.x % (NN / 64)) * 64;
    const int r    = lane >> 4;
    const int q4   = (lane & 15) * 4;

    const float4 sc = *(const float4*)&params[q4];
    const float4 sh = *(const float4*)&params[64 + q4];

    __shared__ float tile[64 * 65];
    const unsigned short* gb = gbf + (size_t)b * NN * 64;
    const int* idxb = idx + b * NN * KK;

    for (int it = 0; it < 4; ++it) {
        const int nbase = n0 + wave * 16 + it * 4;
        const int m_lane = idxb[nbase * 16 + lane];  // lane = r*16+k
        float4 acc = make_float4(0.f, 0.f, 0.f, 0.f);

#pragma unroll
        for (int k = -1; k < 16; ++k) {
            int m = (k < 0) ? (nbase + r) : __shfl(m_lane, (lane & 48) + k, 64);
            uint2 u = *(const uint2*)(gb + (size_t)m * 64 + q4);
            float v0 = __uint_as_float(u.x << 16);
            float v1 = __uint_as_float(u.x & 0xffff0000u);
            float v2 = __uint_as_float(u.y << 16);
            float v3 = __uint_as_float(u.y & 0xffff0000u);
            float t0 = fmaf(v0, sc.x, sh.x);
            float t1 = fmaf(v1, sc.y, sh.y);
            float t2 = fmaf(v2, sc.z, sh.z);
            float t3 = fmaf(v3, sc.w, sh.w);
            acc.x += fmaxf(t0, 0.2f * t0);
            acc.y += fmaxf(t1, 0.2f * t1);
            acc.z += fmaxf(t2, 0.2f * t2);
            acc.w += fmaxf(t3, 0.2f * t3);
        }
        const int row = wave * 16 + it * 4 + r;
        tile[row * 65 + q4 + 0] = acc.x;
        tile[row * 65 + q4 + 1] = acc.y;
        tile[row * 65 + q4 + 2] = acc.z;
        tile[row * 65 + q4 + 3] = acc.w;
    }
    __syncthreads();
    const int j   = tid & 63;
    const int sub = tid >> 6;
#pragma unroll
    for (int ob = 0; ob < 16; ++ob) {
        int o = ob * 4 + sub;
        out[(size_t)(b * 64 + o) * NN + n0 + j] = tile[j * 65 + o];
    }
}

extern "C" void kernel_launch(void* const* d_in, const int* in_sizes, int n_in,
                              void* d_out, int out_size, void* d_ws, size_t ws_size,
                              hipStream_t stream) {
    const float* feat  = (const float*)d_in[0];
    const float* W     = (const float*)d_in[1];
    const float* gamma = (const float*)d_in[2];
    const float* beta  = (const float*)d_in[3];
    const int*   idx   = (const int*)d_in[4];
    float* out = (float*)d_out;

    char* ws = (char*)d_ws;
    unsigned short* gbf = (unsigned short*)ws;
    size_t off = (size_t)BB * NN * 64 * sizeof(unsigned short);   // 20,971,520
    int* cnt = (int*)(ws + off);
    off += (size_t)BB * NN * sizeof(int);                         // +655,360
    float* partials = (float*)(ws + off);
    off += (size_t)GBLK * 128 * sizeof(float);                    // +327,680
    float* params = (float*)(ws + off);

    hipMemsetAsync(cnt, 0, (size_t)BB * NN * sizeof(int), stream);
    k_count<<<(BB * NN * KK + 255) / 256, 256, 0, stream>>>(idx, cnt);
    k_gemm<<<GBLK, 256, 0, stream>>>(feat, W, cnt, gbf, partials);
    k_finalize<<<1, 1024, 0, stream>>>(partials, gamma, beta, params);
    k_final<<<(BB * NN) / 64, 256, 0, stream>>>(gbf, idx, params, out);
}

// Round 4
// 178.187 us; speedup vs baseline: 3.3754x; 1.4727x over previous
//
#include <hip/hip_runtime.h>

#define BB 4
#define CIN 64
#define COUT 64
#define NN 40960
#define KK 16
#define GBLK (BB * NN / 256)   // 640 k_gemm blocks
#define FPAD 264
#define WPAD 68
#define HP 16                  // idx shares per batch
#define HR 4                   // bin ranges per batch
#define HBINS (NN / HR)        // 10240 bins per range

// Privatized histogram: block (b,p,r) bins its idx share for range r into LDS,
// writes private hist to ws (no global atomics).
__global__ __launch_bounds__(256) void k_hist(const int* __restrict__ idx,
                                              unsigned int* __restrict__ hist) {
    __shared__ unsigned int bins[HBINS];   // 40 KB
    const int tid = threadIdx.x;
    const int b = blockIdx.x >> 6;
    const int p = (blockIdx.x >> 2) & 15;
    const int r = blockIdx.x & 3;
    const int lo = r * HBINS;

#pragma unroll
    for (int i = 0; i < HBINS / 256; ++i) bins[i * 256 + tid] = 0u;
    __syncthreads();

    const int4* src = (const int4*)(idx + (size_t)b * NN * KK + (size_t)p * (NN * KK / HP));
#pragma unroll 4
    for (int i = 0; i < (NN * KK / HP) / 4 / 256; ++i) {
        int4 v = src[i * 256 + tid];
        unsigned a0 = (unsigned)(v.x - lo), a1 = (unsigned)(v.y - lo);
        unsigned a2 = (unsigned)(v.z - lo), a3 = (unsigned)(v.w - lo);
        if (a0 < HBINS) atomicAdd(&bins[a0], 1u);
        if (a1 < HBINS) atomicAdd(&bins[a1], 1u);
        if (a2 < HBINS) atomicAdd(&bins[a2], 1u);
        if (a3 < HBINS) atomicAdd(&bins[a3], 1u);
    }
    __syncthreads();
    unsigned int* dst = hist + (size_t)blockIdx.x * HBINS;
#pragma unroll
    for (int i = 0; i < HBINS / 256; ++i) dst[i * 256 + tid] = bins[i * 256 + tid];
}

__device__ __forceinline__ unsigned bf16_rne(float x) {
    unsigned u = __float_as_uint(x);
    return (u + 0x7fffu + ((u >> 16) & 1u)) >> 16;
}

// g[b][n][o] (bf16) = sum_c W[o][c]*feat[b][c][n]; fused weighted stats.
__global__ __launch_bounds__(256) void k_gemm(const float* __restrict__ feat,
                                              const float* __restrict__ W,
                                              const unsigned int* __restrict__ hist,
                                              unsigned short* __restrict__ gbf,
                                              float* __restrict__ partials) {
    __shared__ float Wt_s[64 * WPAD];
    __shared__ float feat_s[16 * FPAD];  // reused as red[2][64][33] in epilogue
    __shared__ float w_s[256];

    const int tid = threadIdx.x;
    const int b   = blockIdx.x / (NN / 256);
    const int n0  = (blockIdx.x % (NN / 256)) * 256;

    // merge private histograms for this block's 256 bins -> w_s
    {
        const int n = n0 + tid;
        const int r = n / HBINS;       // uniform within block (n0%256==0, HBINS%256==0)
        const int ml = n - r * HBINS;
        unsigned s = 1u;
#pragma unroll
        for (int p = 0; p < HP; ++p)
            s += hist[(size_t)(b * 64 + p * 4 + r) * HBINS + ml];
        w_s[tid] = (float)s;
    }

    // stage W transposed (coalesced read, once)
#pragma unroll
    for (int it = 0; it < 16; ++it) {
        int c = tid & 63;
        int o = it * 4 + (tid >> 6);
        Wt_s[c * WPAD + o] = W[o * 64 + c];
    }

    const int to = tid & 7;
    const int tn = tid >> 3;

    float acc[8][8];
#pragma unroll
    for (int i = 0; i < 8; ++i)
#pragma unroll
        for (int j = 0; j < 8; ++j) acc[i][j] = 0.f;

    const float* fb = feat + (size_t)b * CIN * NN + n0;

    for (int cc0 = 0; cc0 < 64; cc0 += 16) {
        __syncthreads();
        {
            int row = tid >> 4;
            int col = (tid & 15) * 4;
            const float* src = fb + (size_t)(cc0 + row) * NN + col;
#pragma unroll
            for (int q = 0; q < 4; ++q) {
                float4 v = *(const float4*)(src + q * 64);
                *(float4*)&feat_s[row * FPAD + col + q * 64] = v;
            }
        }
        __syncthreads();

#pragma unroll
        for (int cc = 0; cc < 16; ++cc) {
            int c = cc0 + cc;
            float4 w0 = *(const float4*)&Wt_s[c * WPAD + to * 8];
            float4 w1 = *(const float4*)&Wt_s[c * WPAD + to * 8 + 4];
            float4 f0 = *(const float4*)&feat_s[cc * FPAD + tn * 8];
            float4 f1 = *(const float4*)&feat_s[cc * FPAD + tn * 8 + 4];
            float wv[8] = {w0.x, w0.y, w0.z, w0.w, w1.x, w1.y, w1.z, w1.w};
            float fv[8] = {f0.x, f0.y, f0.z, f0.w, f1.x, f1.y, f1.z, f1.w};
#pragma unroll
            for (int i = 0; i < 8; ++i)
#pragma unroll
                for (int j = 0; j < 8; ++j)
                    acc[i][j] = fmaf(wv[i], fv[j], acc[i][j]);
        }
    }

    unsigned short* gb = gbf + ((size_t)b * NN + n0) * 64;
#pragma unroll
    for (int j = 0; j < 8; ++j) {
        int n = tn * 8 + j;
        uint4 pk;
        pk.x = bf16_rne(acc[0][j]) | (bf16_rne(acc[1][j]) << 16);
        pk.y = bf16_rne(acc[2][j]) | (bf16_rne(acc[3][j]) << 16);
        pk.z = bf16_rne(acc[4][j]) | (bf16_rne(acc[5][j]) << 16);
        pk.w = bf16_rne(acc[6][j]) | (bf16_rne(acc[7][j]) << 16);
        *(uint4*)&gb[(size_t)n * 64 + to * 8] = pk;
    }

    // fused weighted stats: w = cnt+1 (from w_s)
    float wgt[8];
#pragma unroll
    for (int j = 0; j < 8; ++j) wgt[j] = w_s[tn * 8 + j];
    float s1[8], s2[8];
#pragma unroll
    for (int i = 0; i < 8; ++i) { s1[i] = 0.f; s2[i] = 0.f; }
#pragma unroll
    for (int j = 0; j < 8; ++j)
#pragma unroll
        for (int i = 0; i < 8; ++i) {
            float wv = wgt[j] * acc[i][j];
            s1[i] += wv;
            s2[i] += wv * acc[i][j];
        }

    __syncthreads();
    float* red = feat_s;  // [2][64][33]
#pragma unroll
    for (int i = 0; i < 8; ++i) {
        int o = to * 8 + i;
        red[o * 33 + tn]        = s1[i];
        red[2112 + o * 33 + tn] = s2[i];
    }
    __syncthreads();
    if (tid < 128) {
        int arr = tid >> 6, o = tid & 63;
        const float* base = red + arr * 2112 + o * 33;
        float s = 0.f;
#pragma unroll
        for (int t = 0; t < 32; ++t) s += base[t];
        partials[blockIdx.x * 128 + arr * 64 + o] = s;
    }
}

__global__ __launch_bounds__(1024) void k_finalize(const float* __restrict__ partials,
                                                   const float* __restrict__ gamma,
                                                   const float* __restrict__ beta,
                                                   float* __restrict__ params) {
    const int i = threadIdx.x & 127;
    const int r = threadIdx.x >> 7;
    double a0 = 0, a1 = 0, a2 = 0, a3 = 0;
    for (int base = r; base < GBLK; base += 32) {
        a0 += (double)partials[(base)      * 128 + i];
        a1 += (double)partials[(base + 8)  * 128 + i];
        a2 += (double)partials[(base + 16) * 128 + i];
        a3 += (double)partials[(base + 24) * 128 + i];
    }
    __shared__ double red[8][128];
    red[r][i] = (a0 + a1) + (a2 + a3);
    __syncthreads();
    if (threadIdx.x < 64) {
        const int o = threadIdx.x;
        double s1 = 0.0, s2 = 0.0;
#pragma unroll
        for (int rr = 0; rr < 8; ++rr) { s1 += red[rr][o]; s2 += red[rr][64 + o]; }
        const double TOT = (double)BB * NN * (KK + 1);
        double mean = s1 / TOT;
        double var  = s2 / TOT - mean * mean;
        double inv  = 1.0 / sqrt(var + 1e-6);
        float scale = (float)inv * gamma[o];
        float shift = beta[o] - (float)mean * scale;
        params[o]      = scale;
        params[64 + o] = shift;
    }
}

// out[b][o][n] = sum over {n, idx[b,n,:]} of leakyrelu(g*scale+shift)
// lane: r=lane>>3 selects n-sub, q8=(lane&7)*8 selects channel octet (dwordx4 gathers)
__global__ __launch_bounds__(256) void k_final(const unsigned short* __restrict__ gbf,
                                               const int* __restrict__ idx,
                                               const float* __restrict__ params,
                                               float* __restrict__ out) {
    const int tid  = threadIdx.x;
    const int lane = tid & 63;
    const int wave = tid >> 6;
    const int b    = blockIdx.x / (NN / 64);
    const int n0   = (blockIdx.x % (NN / 64)) * 64;

    __shared__ int   idx_s[64 * 17];   // pitch 17: conflict-free broadcast reads
    __shared__ float tile[64 * 68];

    // stage idx (1024 ints), scalar coalesced, into padded rows
    {
        const int* src = idx + ((size_t)b * NN + n0) * KK;
#pragma unroll
        for (int i = 0; i < 4; ++i) {
            int e = tid * 4 + i;             // 0..1023
            idx_s[(e >> 4) * 17 + (e & 15)] = src[e];
        }
    }

    const int r  = lane >> 3;
    const int q8 = (lane & 7) * 8;
    float sc[8], sh[8];
#pragma unroll
    for (int c = 0; c < 8; ++c) { sc[c] = params[q8 + c]; sh[c] = params[64 + q8 + c]; }
    __syncthreads();

    const unsigned short* gb = gbf + (size_t)b * NN * 64;

#pragma unroll
    for (int rr = 0; rr < 2; ++rr) {
        const int nl = wave * 16 + rr * 8 + r;  // local n 0..63
        float a[8];
#pragma unroll
        for (int c = 0; c < 8; ++c) a[c] = 0.f;

#pragma unroll
        for (int k = -1; k < KK; ++k) {
            int m = (k < 0) ? (n0 + nl) : idx_s[nl * 17 + k];
            uint4 u = *(const uint4*)(gb + (size_t)m * 64 + q8);
            unsigned uw[4] = {u.x, u.y, u.z, u.w};
#pragma unroll
            for (int h = 0; h < 4; ++h) {
                float v0 = __uint_as_float(uw[h] << 16);
                float v1 = __uint_as_float(uw[h] & 0xffff0000u);
                float t0 = fmaf(v0, sc[2 * h],     sh[2 * h]);
                float t1 = fmaf(v1, sc[2 * h + 1], sh[2 * h + 1]);
                a[2 * h]     += fmaxf(t0, 0.2f * t0);
                a[2 * h + 1] += fmaxf(t1, 0.2f * t1);
            }
        }
        *(float4*)&tile[nl * 68 + q8]     = make_float4(a[0], a[1], a[2], a[3]);
        *(float4*)&tile[nl * 68 + q8 + 4] = make_float4(a[4], a[5], a[6], a[7]);
    }
    __syncthreads();
    const int j   = tid & 63;
    const int sub = tid >> 6;
#pragma unroll
    for (int ob = 0; ob < 16; ++ob) {
        int o = ob * 4 + sub;
        out[(size_t)(b * 64 + o) * NN + n0 + j] = tile[j * 68 + o];
    }
}

extern "C" void kernel_launch(void* const* d_in, const int* in_sizes, int n_in,
                              void* d_out, int out_size, void* d_ws, size_t ws_size,
                              hipStream_t stream) {
    const float* feat  = (const float*)d_in[0];
    const float* W     = (const float*)d_in[1];
    const float* gamma = (const float*)d_in[2];
    const float* beta  = (const float*)d_in[3];
    const int*   idx   = (const int*)d_in[4];
    float* out = (float*)d_out;

    char* ws = (char*)d_ws;
    unsigned short* gbf = (unsigned short*)ws;
    size_t off = (size_t)BB * NN * 64 * sizeof(unsigned short);       // 20,971,520
    unsigned int* hist = (unsigned int*)(ws + off);
    off += (size_t)BB * HP * HR * HBINS * sizeof(unsigned int);       // +10,485,760
    float* partials = (float*)(ws + off);
    off += (size_t)GBLK * 128 * sizeof(float);                        // +327,680
    float* params = (float*)(ws + off);

    k_hist<<<BB * HP * HR, 256, 0, stream>>>(idx, hist);
    k_gemm<<<GBLK, 256, 0, stream>>>(feat, W, hist, gbf, partials);
    k_finalize<<<1, 1024, 0, stream>>>(partials, gamma, beta, params);
    k_final<<<(BB * NN) / 64, 256, 0, stream>>>(gbf, idx, params, out);
}

// Round 6
// 158.337 us; speedup vs baseline: 3.7985x; 1.1254x over previous
//
#include <hip/hip_runtime.h>
#include <hip/hip_fp16.h>

typedef _Float16 h2 __attribute__((ext_vector_type(2)));

#define BB 4
#define CIN 64
#define COUT 64
#define NN 40960
#define KK 16
#define GBLK (BB * NN / 256)   // 640 k_gemm blocks
#define FPAD 264
#define WPAD 68
#define HP 32                  // idx shares per batch
#define HR 2                   // bin ranges per batch
#define HBINS (NN / HR)        // 20480 bins per range
#define HWORDS (HBINS / 2)     // 10240 u32 words (2 u16 bins per word)

// Privatized histogram, u16-packed: block (b,p,r) bins its idx share for
// range r into 40KB LDS, plain stores to ws. No global atomics.
// Overflow-safe: share = 20480 elements < 65536.
__global__ __launch_bounds__(256) void k_hist(const int* __restrict__ idx,
                                              unsigned int* __restrict__ hist) {
    __shared__ unsigned int bins[HWORDS];   // 40 KB
    const int tid = threadIdx.x;
    const int b = blockIdx.x >> 6;              // HP*HR = 64
    const int p = (blockIdx.x >> 1) & (HP - 1);
    const int r = blockIdx.x & (HR - 1);
    const int lo = r * HBINS;

#pragma unroll
    for (int i = 0; i < HWORDS / 256; ++i) bins[i * 256 + tid] = 0u;
    __syncthreads();

    const int SHARE = NN * KK / HP;             // 20480
    const int4* src = (const int4*)(idx + (size_t)b * NN * KK + (size_t)p * SHARE);
#pragma unroll 4
    for (int i = 0; i < SHARE / 4 / 256; ++i) { // 20 iters
        int4 v = src[i * 256 + tid];
        unsigned a0 = (unsigned)(v.x - lo), a1 = (unsigned)(v.y - lo);
        unsigned a2 = (unsigned)(v.z - lo), a3 = (unsigned)(v.w - lo);
        if (a0 < HBINS) atomicAdd(&bins[a0 >> 1], 1u << ((a0 & 1) * 16));
        if (a1 < HBINS) atomicAdd(&bins[a1 >> 1], 1u << ((a1 & 1) * 16));
        if (a2 < HBINS) atomicAdd(&bins[a2 >> 1], 1u << ((a2 & 1) * 16));
        if (a3 < HBINS) atomicAdd(&bins[a3 >> 1], 1u << ((a3 & 1) * 16));
    }
    __syncthreads();
    unsigned int* dst = hist + (size_t)blockIdx.x * HWORDS;
#pragma unroll
    for (int i = 0; i < HWORDS / 256; ++i) dst[i * 256 + tid] = bins[i * 256 + tid];
}

// g[b][n][o] (fp16) = sum_c W[o][c]*feat[b][c][n]; fused weighted stats.
__global__ __launch_bounds__(256) void k_gemm(const float* __restrict__ feat,
                                              const float* __restrict__ W,
                                              const unsigned int* __restrict__ hist,
                                              __half* __restrict__ g,
                                              float* __restrict__ partials) {
    __shared__ float Wt_s[64 * WPAD];
    __shared__ float feat_s[16 * FPAD];  // reused as red[2][64][33] in epilogue
    __shared__ float w_s[256];

    const int tid = threadIdx.x;
    const int b   = blockIdx.x / (NN / 256);
    const int n0  = (blockIdx.x % (NN / 256)) * 256;

    // merge u16-packed private histograms for this block's 256 bins
    {
        const int n  = n0 + tid;
        const int r  = n / HBINS;            // uniform within block
        const int ml = n - r * HBINS;
        const int w  = ml >> 1;
        const int sh = (ml & 1) * 16;
        unsigned s = 1u;                     // +1 self reference
#pragma unroll
        for (int p = 0; p < HP; ++p)
            s += (hist[(size_t)((b * HP + p) * HR + r) * HWORDS + w] >> sh) & 0xffffu;
        w_s[tid] = (float)s;
    }

    // stage W transposed (coalesced read, once)
#pragma unroll
    for (int it = 0; it < 16; ++it) {
        int c = tid & 63;
        int o = it * 4 + (tid >> 6);
        Wt_s[c * WPAD + o] = W[o * 64 + c];
    }

    const int to = tid & 7;
    const int tn = tid >> 3;

    float acc[8][8];
#pragma unroll
    for (int i = 0; i < 8; ++i)
#pragma unroll
        for (int j = 0; j < 8; ++j) acc[i][j] = 0.f;

    const float* fb = feat + (size_t)b * CIN * NN + n0;

    for (int cc0 = 0; cc0 < 64; cc0 += 16) {
        __syncthreads();
        {
            int row = tid >> 4;
            int col = (tid & 15) * 4;
            const float* src = fb + (size_t)(cc0 + row) * NN + col;
#pragma unroll
            for (int q = 0; q < 4; ++q) {
                float4 v = *(const float4*)(src + q * 64);
                *(float4*)&feat_s[row * FPAD + col + q * 64] = v;
            }
        }
        __syncthreads();

#pragma unroll
        for (int cc = 0; cc < 16; ++cc) {
            int c = cc0 + cc;
            float4 w0 = *(const float4*)&Wt_s[c * WPAD + to * 8];
            float4 w1 = *(const float4*)&Wt_s[c * WPAD + to * 8 + 4];
            float4 f0 = *(const float4*)&feat_s[cc * FPAD + tn * 8];
            float4 f1 = *(const float4*)&feat_s[cc * FPAD + tn * 8 + 4];
            float wv[8] = {w0.x, w0.y, w0.z, w0.w, w1.x, w1.y, w1.z, w1.w};
            float fv[8] = {f0.x, f0.y, f0.z, f0.w, f1.x, f1.y, f1.z, f1.w};
#pragma unroll
            for (int i = 0; i < 8; ++i)
#pragma unroll
                for (int j = 0; j < 8; ++j)
                    acc[i][j] = fmaf(wv[i], fv[j], acc[i][j]);
        }
    }

    // store g fp16: 8 lanes (to) cover one 128B row
    __half* gb = g + ((size_t)b * NN + n0) * 64;
#pragma unroll
    for (int j = 0; j < 8; ++j) {
        int n = tn * 8 + j;
        union { uint4 u; h2 h[4]; } P;
#pragma unroll
        for (int h = 0; h < 4; ++h) {
            h2 t;
            t.x = (_Float16)acc[2 * h][j];
            t.y = (_Float16)acc[2 * h + 1][j];
            P.h[h] = t;
        }
        *(uint4*)&gb[(size_t)n * 64 + to * 8] = P.u;
    }

    // fused weighted stats (fp32 accumulators, pre-rounding)
    float wgt[8];
#pragma unroll
    for (int j = 0; j < 8; ++j) wgt[j] = w_s[tn * 8 + j];
    float s1[8], s2[8];
#pragma unroll
    for (int i = 0; i < 8; ++i) { s1[i] = 0.f; s2[i] = 0.f; }
#pragma unroll
    for (int j = 0; j < 8; ++j)
#pragma unroll
        for (int i = 0; i < 8; ++i) {
            float wv = wgt[j] * acc[i][j];
            s1[i] += wv;
            s2[i] += wv * acc[i][j];
        }

    __syncthreads();
    float* red = feat_s;  // [2][64][33]
#pragma unroll
    for (int i = 0; i < 8; ++i) {
        int o = to * 8 + i;
        red[o * 33 + tn]        = s1[i];
        red[2112 + o * 33 + tn] = s2[i];
    }
    __syncthreads();
    if (tid < 128) {
        int arr = tid >> 6, o = tid & 63;
        const float* base = red + arr * 2112 + o * 33;
        float s = 0.f;
#pragma unroll
        for (int t = 0; t < 32; ++t) s += base[t];
        partials[blockIdx.x * 128 + arr * 64 + o] = s;
    }
}

__global__ __launch_bounds__(1024) void k_finalize(const float* __restrict__ partials,
                                                   const float* __restrict__ gamma,
                                                   const float* __restrict__ beta,
                                                   _Float16* __restrict__ params_h) {
    const int i = threadIdx.x & 127;
    const int r = threadIdx.x >> 7;
    double a0 = 0, a1 = 0, a2 = 0, a3 = 0;
    for (int base = r; base < GBLK; base += 32) {
        a0 += (double)partials[(base)      * 128 + i];
        a1 += (double)partials[(base + 8)  * 128 + i];
        a2 += (double)partials[(base + 16) * 128 + i];
        a3 += (double)partials[(base + 24) * 128 + i];
    }
    __shared__ double red[8][128];
    red[r][i] = (a0 + a1) + (a2 + a3);
    __syncthreads();
    if (threadIdx.x < 64) {
        const int o = threadIdx.x;
        double s1 = 0.0, s2 = 0.0;
#pragma unroll
        for (int rr = 0; rr < 8; ++rr) { s1 += red[rr][o]; s2 += red[rr][64 + o]; }
        const double TOT = (double)BB * NN * (KK + 1);
        double mean = s1 / TOT;
        double var  = s2 / TOT - mean * mean;
        double inv  = 1.0 / sqrt(var + 1e-6);
        float scale = (float)inv * gamma[o];
        float shift = beta[o] - (float)mean * scale;
        params_h[o]      = (_Float16)scale;
        params_h[64 + o] = (_Float16)shift;
    }
}

// out[b][o][n] = sum over {n, idx[b,n,:]} of leakyrelu(g*scale+shift)
// packed-fp16 math (v_pk_fma/v_pk_max); XCD-partitioned: b = (blockIdx&7)>>1.
__global__ __launch_bounds__(256) void k_final(const __half* __restrict__ g,
                                               const int* __restrict__ idx,
                                               const _Float16* __restrict__ params_h,
                                               float* __restrict__ out) {
    const int tid  = threadIdx.x;
    const int lane = tid & 63;
    const int wave = tid >> 6;
    const int b     = (blockIdx.x & 7) >> 1;                       // 2 XCDs per batch
    const int chunk = ((blockIdx.x >> 3) << 1) | (blockIdx.x & 1); // 0..639
    const int n0    = chunk * 64;

    __shared__ int   idx_s[64 * 17];   // pitch 17: conflict-free broadcast reads
    __shared__ float tile[64 * 65];    // pitch 65: <=2-way on write & transpose read

    // stage idx (1024 ints) via int4, coalesced
    {
        const int4* src = (const int4*)(idx + ((size_t)b * NN + n0) * KK);
        int4 v = src[tid];
        int row = tid >> 2, col = (tid & 3) * 4;
        idx_s[row * 17 + col + 0] = v.x;
        idx_s[row * 17 + col + 1] = v.y;
        idx_s[row * 17 + col + 2] = v.z;
        idx_s[row * 17 + col + 3] = v.w;
    }

    const int r  = lane >> 3;
    const int q8 = (lane & 7) * 8;
    h2 sc2[4], sh2[4];
#pragma unroll
    for (int h = 0; h < 4; ++h) {
        h2 a, s;
        a.x = params_h[q8 + 2 * h];     a.y = params_h[q8 + 2 * h + 1];
        s.x = params_h[64 + q8 + 2 * h]; s.y = params_h[64 + q8 + 2 * h + 1];
        sc2[h] = a; sh2[h] = s;
    }
    __syncthreads();

    const __half* gb = g + (size_t)b * NN * 64;

#pragma unroll
    for (int rr = 0; rr < 2; ++rr) {
        const int nl = wave * 16 + rr * 8 + r;  // local n 0..63
        h2 acc[4];
#pragma unroll
        for (int h = 0; h < 4; ++h) acc[h] = (h2)(_Float16)0;

#pragma unroll
        for (int k = -1; k < KK; ++k) {
            int m = (k < 0) ? (n0 + nl) : idx_s[nl * 17 + k];
            union { uint4 u; h2 h[4]; } U;
            U.u = *(const uint4*)(gb + (size_t)m * 64 + q8);
#pragma unroll
            for (int h = 0; h < 4; ++h) {
                h2 t = U.h[h] * sc2[h] + sh2[h];
                acc[h] += __builtin_elementwise_max(t, t * (_Float16)0.2f);
            }
        }
        float* tr = &tile[nl * 65 + q8];
#pragma unroll
        for (int h = 0; h < 4; ++h) {
            tr[2 * h]     = (float)acc[h].x;
            tr[2 * h + 1] = (float)acc[h].y;
        }
    }
    __syncthreads();
    const int j   = tid & 63;
    const int sub = tid >> 6;
#pragma unroll
    for (int ob = 0; ob < 16; ++ob) {
        int o = ob * 4 + sub;
        out[(size_t)(b * 64 + o) * NN + n0 + j] = tile[j * 65 + o];
    }
}

extern "C" void kernel_launch(void* const* d_in, const int* in_sizes, int n_in,
                              void* d_out, int out_size, void* d_ws, size_t ws_size,
                              hipStream_t stream) {
    const float* feat  = (const float*)d_in[0];
    const float* W     = (const float*)d_in[1];
    const float* gamma = (const float*)d_in[2];
    const float* beta  = (const float*)d_in[3];
    const int*   idx   = (const int*)d_in[4];
    float* out = (float*)d_out;

    char* ws = (char*)d_ws;
    __half* g = (__half*)ws;
    size_t off = (size_t)BB * NN * 64 * sizeof(__half);               // 20,971,520
    unsigned int* hist = (unsigned int*)(ws + off);
    off += (size_t)BB * HP * HR * HWORDS * sizeof(unsigned int);      // +10,485,760
    float* partials = (float*)(ws + off);
    off += (size_t)GBLK * 128 * sizeof(float);                        // +327,680
    _Float16* params_h = (_Float16*)(ws + off);

    k_hist<<<BB * HP * HR, 256, 0, stream>>>(idx, hist);
    k_gemm<<<GBLK, 256, 0, stream>>>(feat, W, hist, g, partials);
    k_finalize<<<1, 1024, 0, stream>>>(partials, gamma, beta, params_h);
    k_final<<<(BB * NN) / 64, 256, 0, stream>>>(g, idx, params_h, out);
}